// Round 6
// baseline (311.402 us; speedup 1.0000x reference)
//
#include <hip/hip_runtime.h>

#define EDIM 64
#define CHUNK 4096          // edges per Phase-A block
#define BSH 9               // bucket = col >> 9  (512 cols/bucket)
#define BCOLS 512
#define CAP 8192            // per-bucket pair capacity (avg ~6400, +22 sigma)

// ---------- bf16 helpers (bit ops, RNE) ----------
__device__ __forceinline__ unsigned f2_to_bf2(float a, float b) {
    unsigned ua = __float_as_uint(a); ua += 0x7fffu + ((ua >> 16) & 1u);
    unsigned ub = __float_as_uint(b); ub += 0x7fffu + ((ub >> 16) & 1u);
    return (ua >> 16) | (ub & 0xffff0000u);
}
__device__ __forceinline__ float bf_lo(unsigned u) { return __uint_as_float(u << 16); }
__device__ __forceinline__ float bf_hi(unsigned u) { return __uint_as_float(u & 0xffff0000u); }

// ---------- bucket cursor init ----------
__global__ void k_binit(int* __restrict__ bcur, int nb) {
    int b = threadIdx.x;
    if (b < nb) bcur[b] = b * CAP;
}

// ---------- Phase A: LDS bucket-sort chunks, coalesced runs ----------
// buf.x = row | (bucket << 24); pairs.y = (edge_id << 9) | (col & 511)
__global__ __launch_bounds__(256) void k_binA(const int* __restrict__ row, const int* __restrict__ col,
                                              int* __restrict__ bcur, uint2* __restrict__ pairs,
                                              int E, int nb) {
    __shared__ uint2 buf[CHUNK];
    __shared__ int histL[256], baseL[256], curL[256], gbaseL[256];
    __shared__ int wsum[4];
    int tid = threadIdx.x;
    int c0 = blockIdx.x * CHUNK;
    int cend = min(CHUNK, E - c0);

    histL[tid] = 0;
    __syncthreads();

    int myr[CHUNK / 256], myc[CHUNK / 256];
    #pragma unroll
    for (int k = 0; k < CHUNK / 256; ++k) {
        int i = k * 256 + tid;
        if (i < cend) {
            int e = c0 + i;
            myr[k] = row[e]; myc[k] = col[e];
            atomicAdd(&histL[myc[k] >> BSH], 1);
        }
    }
    __syncthreads();

    int v = histL[tid];
    int lane = tid & 63, w = tid >> 6;
    int inc = v;
    #pragma unroll
    for (int d = 1; d < 64; d <<= 1) { int t = __shfl_up(inc, d, 64); if (lane >= d) inc += t; }
    if (lane == 63) wsum[w] = inc;
    __syncthreads();
    int woff = 0;
    for (int i = 0; i < w; ++i) woff += wsum[i];
    int excl = inc - v + woff;
    baseL[tid] = excl;
    curL[tid] = excl;
    if (tid < nb) gbaseL[tid] = atomicAdd(&bcur[tid], v);
    __syncthreads();

    #pragma unroll
    for (int k = 0; k < CHUNK / 256; ++k) {
        int i = k * 256 + tid;
        if (i < cend) {
            int b = myc[k] >> BSH;
            int e = c0 + i;
            int pos = atomicAdd(&curL[b], 1);
            buf[pos] = make_uint2((unsigned)myr[k] | ((unsigned)b << 24),
                                  ((unsigned)e << 9) | ((unsigned)myc[k] & (BCOLS - 1)));
        }
    }
    __syncthreads();

    for (int i = tid; i < cend; i += 256) {
        uint2 p = buf[i];
        int b = (int)(p.x >> 24);
        int dst = gbaseL[b] + (i - baseL[b]);
        pairs[dst] = make_uint2(p.x & 0x00FFFFFFu, p.y);
    }
}

// ---------- tiny scan over bucket counts ----------
__global__ void k_bscan(const int* __restrict__ bcur, int* __restrict__ bbase, int nb) {
    __shared__ int wsum[4];
    int tid = threadIdx.x;
    int v = (tid < nb) ? (bcur[tid] - tid * CAP) : 0;
    int lane = tid & 63, w = tid >> 6;
    int inc = v;
    #pragma unroll
    for (int d = 1; d < 64; d <<= 1) { int t = __shfl_up(inc, d, 64); if (lane >= d) inc += t; }
    if (lane == 63) wsum[w] = inc;
    __syncthreads();
    int woff = 0;
    for (int i = 0; i < w; ++i) woff += wsum[i];
    if (tid < nb) bbase[tid] = inc - v + woff;
}

// ---------- Phase B: per-bucket deg/off/dis/invd + placement (rowp + eidx) ----------
__global__ __launch_bounds__(256) void k_binB(const uint2* __restrict__ pairs,
                                              const int* __restrict__ bcur, const int* __restrict__ bbase,
                                              int* __restrict__ off, float* __restrict__ dis,
                                              float* __restrict__ invd,
                                              int* __restrict__ rowp, int* __restrict__ eidx, int N) {
    __shared__ int degL[BCOLS];
    __shared__ int curL[BCOLS];
    __shared__ int wsum[4];
    int tid = threadIdx.x;
    int b = blockIdx.x;
    int base_in = b * CAP;
    int cnt = bcur[b] - base_in;
    int col0 = b << BSH;
    int ncols = min(BCOLS, N - col0);

    degL[tid] = 0; degL[tid + 256] = 0;
    __syncthreads();

    for (int i = tid; i < cnt; i += 256)
        atomicAdd(&degL[(int)(pairs[base_in + i].y & (BCOLS - 1))], 1);
    __syncthreads();

    int d0 = degL[2 * tid], d1 = degL[2 * tid + 1];
    int v = d0 + d1;
    int lane = tid & 63, w = tid >> 6;
    int inc = v;
    #pragma unroll
    for (int d = 1; d < 64; d <<= 1) { int t = __shfl_up(inc, d, 64); if (lane >= d) inc += t; }
    if (lane == 63) wsum[w] = inc;
    __syncthreads();
    int woff = 0;
    for (int i = 0; i < w; ++i) woff += wsum[i];
    int exclp = inc - v + woff + bbase[b];
    __syncthreads();
    int c0i = 2 * tid, c1i = 2 * tid + 1;
    if (c0i < ncols) {
        off[col0 + c0i] = exclp;
        dis[col0 + c0i] = (d0 > 0) ? rsqrtf((float)d0) : 0.0f;
        invd[col0 + c0i] = (d0 > 0) ? sqrtf((float)d0) : 0.0f;
        curL[c0i] = exclp;
    }
    if (c1i < ncols) {
        off[col0 + c1i] = exclp + d0;
        dis[col0 + c1i] = (d1 > 0) ? rsqrtf((float)d1) : 0.0f;
        invd[col0 + c1i] = (d1 > 0) ? sqrtf((float)d1) : 0.0f;
        curL[c1i] = exclp + d0;
    }
    __syncthreads();

    for (int i = tid; i < cnt; i += 256) {
        uint2 p = pairs[base_in + i];
        int pos = atomicAdd(&curL[(int)(p.y & (BCOLS - 1))], 1);
        rowp[pos] = (int)p.x;
        eidx[pos] = (int)(p.y >> 9);
    }
}

// ---------- y0 = bf16(dis[n] * emb[n][:]) ----------
__global__ __launch_bounds__(256) void k_cvty(const float* __restrict__ emb,
                                              const float* __restrict__ dis,
                                              unsigned* __restrict__ y0, int n16) {
    int i = blockIdx.x * blockDim.x + threadIdx.x;
    if (i < n16) {
        float d = dis[i >> 4];
        float4 v = ((const float4*)emb)[i];
        uint2 o; o.x = f2_to_bf2(d * v.x, d * v.y); o.y = f2_to_bf2(d * v.z, d * v.w);
        ((uint2*)y0)[i] = o;
    }
}

// ---------- gather layer (8 edges in flight per half-wave) ----------
__global__ __launch_bounds__(256) void k_prop(const int* __restrict__ off, const int* __restrict__ rowp,
                                              const float* __restrict__ dis, const float* __restrict__ invd,
                                              const unsigned short* __restrict__ yin,
                                              unsigned short* __restrict__ yout,
                                              const float* __restrict__ emb,
                                              const unsigned short* __restrict__ y1,
                                              const unsigned short* __restrict__ y2,
                                              const float* __restrict__ alpha,
                                              unsigned short* __restrict__ out16,
                                              int N, int E, int last) {
    int wid = (blockIdx.x * blockDim.x + threadIdx.x) >> 6;
    if (wid >= N) return;
    int lane = threadIdx.x & 63;
    int h = lane >> 5;           // which edge of the pair
    int s = lane & 31;           // dim-pair index: dims 2s, 2s+1
    int j0 = off[wid];
    int j1 = (wid == N - 1) ? E : off[wid + 1];
    float ax = 0.0f, ay = 0.0f;

    int jj = j0 + h;
    for (; jj + 14 < j1; jj += 16) {
        int r0 = rowp[jj],      r1 = rowp[jj + 2],  r2 = rowp[jj + 4],  r3 = rowp[jj + 6];
        int r4 = rowp[jj + 8],  r5 = rowp[jj + 10], r6 = rowp[jj + 12], r7 = rowp[jj + 14];
        unsigned v0 = *(const unsigned*)(yin + ((size_t)r0 << 6) + (s << 1));
        unsigned v1 = *(const unsigned*)(yin + ((size_t)r1 << 6) + (s << 1));
        unsigned v2 = *(const unsigned*)(yin + ((size_t)r2 << 6) + (s << 1));
        unsigned v3 = *(const unsigned*)(yin + ((size_t)r3 << 6) + (s << 1));
        unsigned v4 = *(const unsigned*)(yin + ((size_t)r4 << 6) + (s << 1));
        unsigned v5 = *(const unsigned*)(yin + ((size_t)r5 << 6) + (s << 1));
        unsigned v6 = *(const unsigned*)(yin + ((size_t)r6 << 6) + (s << 1));
        unsigned v7 = *(const unsigned*)(yin + ((size_t)r7 << 6) + (s << 1));
        ax += bf_lo(v0) + bf_lo(v1) + bf_lo(v2) + bf_lo(v3)
            + bf_lo(v4) + bf_lo(v5) + bf_lo(v6) + bf_lo(v7);
        ay += bf_hi(v0) + bf_hi(v1) + bf_hi(v2) + bf_hi(v3)
            + bf_hi(v4) + bf_hi(v5) + bf_hi(v6) + bf_hi(v7);
    }
    for (; jj < j1; jj += 2) {
        int r = rowp[jj];
        unsigned v = *(const unsigned*)(yin + ((size_t)r << 6) + (s << 1));
        ax += bf_lo(v); ay += bf_hi(v);
    }

    ax += __shfl_xor(ax, 32, 64);
    ay += __shfl_xor(ay, 32, 64);

    if (h == 0) {
        float d = dis[wid];
        size_t oi = ((size_t)wid << 6) + (s << 1);
        if (!last) {
            float sc = d * d;
            *(unsigned*)(yout + oi) = f2_to_bf2(sc * ax, sc * ay);
        } else {
            float iv = invd[wid];
            float a0 = alpha[0], a1 = alpha[1], a2 = alpha[2], a3 = alpha[3];
            float2 e = *(const float2*)(emb + oi);
            unsigned u1 = *(const unsigned*)(y1 + oi);
            unsigned u2 = *(const unsigned*)(y2 + oi);
            float ox = a0 * e.x + iv * (a1 * bf_lo(u1) + a2 * bf_lo(u2)) + a3 * d * ax;
            float oy = a0 * e.y + iv * (a1 * bf_hi(u1) + a2 * bf_hi(u2)) + a3 * d * ay;
            *(unsigned*)(out16 + oi) = f2_to_bf2(ox, oy);
        }
    }
}

// ---------- CSR-ordered dot: 4 edges in flight per 16-lane group ----------
__global__ __launch_bounds__(256) void k_dotc(const int* __restrict__ off, const int* __restrict__ rowp,
                                              const int* __restrict__ eidx,
                                              const unsigned short* __restrict__ out16,
                                              float* __restrict__ res, int N, int E) {
    int wid = (blockIdx.x * blockDim.x + threadIdx.x) >> 6;
    if (wid >= N) return;
    int lane = threadIdx.x & 63;
    int g = lane >> 4;           // edge group 0..3
    int q = lane & 15;           // dim-quad index: 4 shorts per lane
    int j0 = off[wid];
    int j1 = (wid == N - 1) ? E : off[wid + 1];

    // col-side operand, loaded once per wave
    uint2 bv = *(const uint2*)(out16 + ((size_t)wid << 6) + (q << 2));

    int j = j0 + g;
    for (; j + 12 < j1; j += 16) {
        int r0 = rowp[j],      e0 = eidx[j];
        int r1 = rowp[j + 4],  e1 = eidx[j + 4];
        int r2 = rowp[j + 8],  e2 = eidx[j + 8];
        int r3 = rowp[j + 12], e3 = eidx[j + 12];
        uint2 a0 = *(const uint2*)(out16 + ((size_t)r0 << 6) + (q << 2));
        uint2 a1 = *(const uint2*)(out16 + ((size_t)r1 << 6) + (q << 2));
        uint2 a2 = *(const uint2*)(out16 + ((size_t)r2 << 6) + (q << 2));
        uint2 a3 = *(const uint2*)(out16 + ((size_t)r3 << 6) + (q << 2));
        float t0 = bf_lo(a0.x) * bf_lo(bv.x) + bf_hi(a0.x) * bf_hi(bv.x)
                 + bf_lo(a0.y) * bf_lo(bv.y) + bf_hi(a0.y) * bf_hi(bv.y);
        float t1 = bf_lo(a1.x) * bf_lo(bv.x) + bf_hi(a1.x) * bf_hi(bv.x)
                 + bf_lo(a1.y) * bf_lo(bv.y) + bf_hi(a1.y) * bf_hi(bv.y);
        float t2 = bf_lo(a2.x) * bf_lo(bv.x) + bf_hi(a2.x) * bf_hi(bv.x)
                 + bf_lo(a2.y) * bf_lo(bv.y) + bf_hi(a2.y) * bf_hi(bv.y);
        float t3 = bf_lo(a3.x) * bf_lo(bv.x) + bf_hi(a3.x) * bf_hi(bv.x)
                 + bf_lo(a3.y) * bf_lo(bv.y) + bf_hi(a3.y) * bf_hi(bv.y);
        t0 += __shfl_xor(t0, 1, 16); t1 += __shfl_xor(t1, 1, 16);
        t2 += __shfl_xor(t2, 1, 16); t3 += __shfl_xor(t3, 1, 16);
        t0 += __shfl_xor(t0, 2, 16); t1 += __shfl_xor(t1, 2, 16);
        t2 += __shfl_xor(t2, 2, 16); t3 += __shfl_xor(t3, 2, 16);
        t0 += __shfl_xor(t0, 4, 16); t1 += __shfl_xor(t1, 4, 16);
        t2 += __shfl_xor(t2, 4, 16); t3 += __shfl_xor(t3, 4, 16);
        t0 += __shfl_xor(t0, 8, 16); t1 += __shfl_xor(t1, 8, 16);
        t2 += __shfl_xor(t2, 8, 16); t3 += __shfl_xor(t3, 8, 16);
        if (q == 0) { res[e0] = t0; res[e1] = t1; res[e2] = t2; res[e3] = t3; }
    }
    for (; j < j1; j += 4) {
        int r = rowp[j], e = eidx[j];
        uint2 av = *(const uint2*)(out16 + ((size_t)r << 6) + (q << 2));
        float s = bf_lo(av.x) * bf_lo(bv.x) + bf_hi(av.x) * bf_hi(bv.x)
                + bf_lo(av.y) * bf_lo(bv.y) + bf_hi(av.y) * bf_hi(bv.y);
        s += __shfl_xor(s, 1, 16);
        s += __shfl_xor(s, 2, 16);
        s += __shfl_xor(s, 4, 16);
        s += __shfl_xor(s, 8, 16);
        if (q == 0) res[e] = s;
    }
}

extern "C" void kernel_launch(void* const* d_in, const int* in_sizes, int n_in,
                              void* d_out, int out_size, void* d_ws, size_t ws_size,
                              hipStream_t stream) {
    const int*   edge  = (const int*)d_in[0];     // [2][E]
    const float* emb   = (const float*)d_in[1];   // [N][64]
    const float* alpha = (const float*)d_in[2];   // [4]
    float*       res   = (float*)d_out;           // [E]

    const int E = in_sizes[0] / 2;
    const int N = in_sizes[1] / EDIM;
    const int* row = edge;
    const int* col = edge + E;
    const int NB = (N + BCOLS - 1) >> BSH;        // 196 for N=100k

    // workspace layout (4B words)
    size_t o = 0;
    int*   offA  = (int*)d_ws + o;   o += (size_t)N;
    float* dis   = (float*)d_ws + o; o += (size_t)N;
    float* invd  = (float*)d_ws + o; o += (size_t)N;
    int*   bcur  = (int*)d_ws + o;   o += 256;
    int*   bbase = (int*)d_ws + o;   o += 256;
    int*   rowp  = (int*)d_ws + o;   o += (size_t)E;
    int*   eidx  = (int*)d_ws + o;   o += (size_t)E;
    unsigned short* y0 = (unsigned short*)((int*)d_ws + o); o += (size_t)N * 32;
    unsigned short* y1 = (unsigned short*)((int*)d_ws + o); o += (size_t)N * 32;
    unsigned short* y2 = (unsigned short*)((int*)d_ws + o); o += (size_t)N * 32;
    uint2* pairs = (uint2*)((int*)d_ws + o);      // NB*CAP uint2
    unsigned short* out16 = (unsigned short*)pairs;  // pairs dead after k_binB
    (void)ws_size; (void)n_in;

    const int B = 256;
    const int n16 = N * 16;                       // float4 count of emb

    // CSR build: bin -> scan -> place (emits dis/invd, rowp, eidx)
    k_binit<<<1, 256, 0, stream>>>(bcur, NB);
    k_binA <<<(E + CHUNK - 1) / CHUNK, B, 0, stream>>>(row, col, bcur, pairs, E, NB);
    k_bscan<<<1, 256, 0, stream>>>(bcur, bbase, NB);
    k_binB <<<NB, B, 0, stream>>>(pairs, bcur, bbase, offA, dis, invd, rowp, eidx, N);

    // y0 = bf16(dis * emb)
    k_cvty <<<(n16 + B - 1) / B, B, 0, stream>>>(emb, dis, (unsigned*)y0, n16);

    // three gather layers; last fuses the alpha-combine and emits out16
    k_prop<<<((size_t)N * 64 + B - 1) / B, B, 0, stream>>>(
        offA, rowp, dis, invd, y0, y1, emb, y1, y2, alpha, out16, N, E, 0);
    k_prop<<<((size_t)N * 64 + B - 1) / B, B, 0, stream>>>(
        offA, rowp, dis, invd, y1, y2, emb, y1, y2, alpha, out16, N, E, 0);
    k_prop<<<((size_t)N * 64 + B - 1) / B, B, 0, stream>>>(
        offA, rowp, dis, invd, y2, (unsigned short*)0, emb, y1, y2, alpha, out16, N, E, 1);

    // per-edge dots in CSR order (col operand register-cached)
    k_dotc<<<((size_t)N * 64 + B - 1) / B, B, 0, stream>>>(offA, rowp, eidx, out16, res, N, E);
}

// Round 7
// 194.373 us; speedup vs baseline: 1.6021x; 1.6021x over previous
//
#include <hip/hip_runtime.h>

#define EDIM 64
#define CHUNK 4096          // edges per Phase-A block
#define BSH 9               // bucket = col >> 9  (512 cols/bucket)
#define BCOLS 512
#define CAP 8192            // per-bucket pair capacity (avg ~6400, +22 sigma)

// ---------- bf16 helpers (bit ops, RNE) ----------
__device__ __forceinline__ unsigned f2_to_bf2(float a, float b) {
    unsigned ua = __float_as_uint(a); ua += 0x7fffu + ((ua >> 16) & 1u);
    unsigned ub = __float_as_uint(b); ub += 0x7fffu + ((ub >> 16) & 1u);
    return (ua >> 16) | (ub & 0xffff0000u);
}
__device__ __forceinline__ float bf_lo(unsigned u) { return __uint_as_float(u << 16); }
__device__ __forceinline__ float bf_hi(unsigned u) { return __uint_as_float(u & 0xffff0000u); }

// ---------- bucket cursor init ----------
__global__ void k_binit(int* __restrict__ bcur, int nb) {
    int b = threadIdx.x;
    if (b < nb) bcur[b] = b * CAP;
}

// ---------- Phase A: LDS bucket-sort chunks, coalesced runs ----------
__global__ __launch_bounds__(256) void k_binA(const int* __restrict__ row, const int* __restrict__ col,
                                              int* __restrict__ bcur, uint2* __restrict__ pairs,
                                              int E, int nb) {
    __shared__ uint2 buf[CHUNK];
    __shared__ int histL[256], baseL[256], curL[256], gbaseL[256];
    __shared__ int wsum[4];
    int tid = threadIdx.x;
    int c0 = blockIdx.x * CHUNK;
    int cend = min(CHUNK, E - c0);

    histL[tid] = 0;
    __syncthreads();

    int myr[CHUNK / 256], myc[CHUNK / 256];
    #pragma unroll
    for (int k = 0; k < CHUNK / 256; ++k) {
        int i = k * 256 + tid;
        if (i < cend) {
            int e = c0 + i;
            myr[k] = row[e]; myc[k] = col[e];
            atomicAdd(&histL[myc[k] >> BSH], 1);
        }
    }
    __syncthreads();

    int v = histL[tid];
    int lane = tid & 63, w = tid >> 6;
    int inc = v;
    #pragma unroll
    for (int d = 1; d < 64; d <<= 1) { int t = __shfl_up(inc, d, 64); if (lane >= d) inc += t; }
    if (lane == 63) wsum[w] = inc;
    __syncthreads();
    int woff = 0;
    for (int i = 0; i < w; ++i) woff += wsum[i];
    int excl = inc - v + woff;
    baseL[tid] = excl;
    curL[tid] = excl;
    if (tid < nb) gbaseL[tid] = atomicAdd(&bcur[tid], v);
    __syncthreads();

    #pragma unroll
    for (int k = 0; k < CHUNK / 256; ++k) {
        int i = k * 256 + tid;
        if (i < cend) {
            int b = myc[k] >> BSH;
            int e = c0 + i;
            int pos = atomicAdd(&curL[b], 1);
            buf[pos] = make_uint2((unsigned)myr[k] | ((unsigned)b << 24),
                                  ((unsigned)e << 9) | ((unsigned)myc[k] & (BCOLS - 1)));
        }
    }
    __syncthreads();

    for (int i = tid; i < cend; i += 256) {
        uint2 p = buf[i];
        int b = (int)(p.x >> 24);
        int dst = gbaseL[b] + (i - baseL[b]);
        pairs[dst] = make_uint2(p.x & 0x00FFFFFFu, p.y);
    }
}

// ---------- tiny scan over bucket counts ----------
__global__ void k_bscan(const int* __restrict__ bcur, int* __restrict__ bbase, int nb) {
    __shared__ int wsum[4];
    int tid = threadIdx.x;
    int v = (tid < nb) ? (bcur[tid] - tid * CAP) : 0;
    int lane = tid & 63, w = tid >> 6;
    int inc = v;
    #pragma unroll
    for (int d = 1; d < 64; d <<= 1) { int t = __shfl_up(inc, d, 64); if (lane >= d) inc += t; }
    if (lane == 63) wsum[w] = inc;
    __syncthreads();
    int woff = 0;
    for (int i = 0; i < w; ++i) woff += wsum[i];
    if (tid < nb) bbase[tid] = inc - v + woff;
}

// ---------- Phase B: per-bucket deg/off/dis/invd + placement (rowp + eidx) ----------
__global__ __launch_bounds__(256) void k_binB(const uint2* __restrict__ pairs,
                                              const int* __restrict__ bcur, const int* __restrict__ bbase,
                                              int* __restrict__ off, float* __restrict__ dis,
                                              float* __restrict__ invd,
                                              int* __restrict__ rowp, int* __restrict__ eidx, int N) {
    __shared__ int degL[BCOLS];
    __shared__ int curL[BCOLS];
    __shared__ int wsum[4];
    int tid = threadIdx.x;
    int b = blockIdx.x;
    int base_in = b * CAP;
    int cnt = bcur[b] - base_in;
    int col0 = b << BSH;
    int ncols = min(BCOLS, N - col0);

    degL[tid] = 0; degL[tid + 256] = 0;
    __syncthreads();

    for (int i = tid; i < cnt; i += 256)
        atomicAdd(&degL[(int)(pairs[base_in + i].y & (BCOLS - 1))], 1);
    __syncthreads();

    int d0 = degL[2 * tid], d1 = degL[2 * tid + 1];
    int v = d0 + d1;
    int lane = tid & 63, w = tid >> 6;
    int inc = v;
    #pragma unroll
    for (int d = 1; d < 64; d <<= 1) { int t = __shfl_up(inc, d, 64); if (lane >= d) inc += t; }
    if (lane == 63) wsum[w] = inc;
    __syncthreads();
    int woff = 0;
    for (int i = 0; i < w; ++i) woff += wsum[i];
    int exclp = inc - v + woff + bbase[b];
    __syncthreads();
    int c0i = 2 * tid, c1i = 2 * tid + 1;
    if (c0i < ncols) {
        off[col0 + c0i] = exclp;
        dis[col0 + c0i] = (d0 > 0) ? rsqrtf((float)d0) : 0.0f;
        invd[col0 + c0i] = (d0 > 0) ? sqrtf((float)d0) : 0.0f;
        curL[c0i] = exclp;
    }
    if (c1i < ncols) {
        off[col0 + c1i] = exclp + d0;
        dis[col0 + c1i] = (d1 > 0) ? rsqrtf((float)d1) : 0.0f;
        invd[col0 + c1i] = (d1 > 0) ? sqrtf((float)d1) : 0.0f;
        curL[c1i] = exclp + d0;
    }
    __syncthreads();

    for (int i = tid; i < cnt; i += 256) {
        uint2 p = pairs[base_in + i];
        int pos = atomicAdd(&curL[(int)(p.y & (BCOLS - 1))], 1);
        rowp[pos] = (int)p.x;
        eidx[pos] = (int)(p.y >> 9);
    }
}

// ---------- y0 = bf16(dis[n] * emb[n][:]) ----------
__global__ __launch_bounds__(256) void k_cvty(const float* __restrict__ emb,
                                              const float* __restrict__ dis,
                                              unsigned* __restrict__ y0, int n16) {
    int i = blockIdx.x * blockDim.x + threadIdx.x;
    if (i < n16) {
        float d = dis[i >> 4];
        float4 v = ((const float4*)emb)[i];
        uint2 o; o.x = f2_to_bf2(d * v.x, d * v.y); o.y = f2_to_bf2(d * v.z, d * v.w);
        ((uint2*)y0)[i] = o;
    }
}

// ---------- gather layer: 16 lanes per node (4 nodes/wave), stride-1 unroll-4 ----------
// lane q owns dims 4q..4q+3; no cross-lane reduction needed.
__global__ __launch_bounds__(256) void k_prop(const int* __restrict__ off, const int* __restrict__ rowp,
                                              const float* __restrict__ dis, const float* __restrict__ invd,
                                              const unsigned short* __restrict__ yin,
                                              unsigned short* __restrict__ yout,
                                              const float* __restrict__ emb,
                                              const unsigned short* __restrict__ y1,
                                              const unsigned short* __restrict__ y2,
                                              const float* __restrict__ alpha,
                                              unsigned short* __restrict__ out16,
                                              int N, int E, int last) {
    int t = blockIdx.x * blockDim.x + threadIdx.x;
    int wid = t >> 4;
    if (wid >= N) return;
    int q = threadIdx.x & 15;        // dims 4q..4q+3
    int j0 = off[wid];
    int j1 = (wid == N - 1) ? E : off[wid + 1];
    float ax = 0.0f, ay = 0.0f, az = 0.0f, aw = 0.0f;

    int j = j0;
    for (; j + 3 < j1; j += 4) {
        int r0 = rowp[j], r1 = rowp[j + 1], r2 = rowp[j + 2], r3 = rowp[j + 3];
        uint2 v0 = *(const uint2*)(yin + ((size_t)r0 << 6) + (q << 2));
        uint2 v1 = *(const uint2*)(yin + ((size_t)r1 << 6) + (q << 2));
        uint2 v2 = *(const uint2*)(yin + ((size_t)r2 << 6) + (q << 2));
        uint2 v3 = *(const uint2*)(yin + ((size_t)r3 << 6) + (q << 2));
        ax += bf_lo(v0.x) + bf_lo(v1.x) + bf_lo(v2.x) + bf_lo(v3.x);
        ay += bf_hi(v0.x) + bf_hi(v1.x) + bf_hi(v2.x) + bf_hi(v3.x);
        az += bf_lo(v0.y) + bf_lo(v1.y) + bf_lo(v2.y) + bf_lo(v3.y);
        aw += bf_hi(v0.y) + bf_hi(v1.y) + bf_hi(v2.y) + bf_hi(v3.y);
    }
    for (; j < j1; ++j) {
        int r = rowp[j];
        uint2 v = *(const uint2*)(yin + ((size_t)r << 6) + (q << 2));
        ax += bf_lo(v.x); ay += bf_hi(v.x);
        az += bf_lo(v.y); aw += bf_hi(v.y);
    }

    float d = dis[wid];
    size_t oi = ((size_t)wid << 6) + (q << 2);
    if (!last) {
        float sc = d * d;
        *(uint2*)(yout + oi) = make_uint2(f2_to_bf2(sc * ax, sc * ay),
                                          f2_to_bf2(sc * az, sc * aw));
    } else {
        float iv = invd[wid];
        float a0 = alpha[0], a1 = alpha[1], a2 = alpha[2], a3 = alpha[3];
        float4 e = *(const float4*)(emb + oi);
        uint2 u1 = *(const uint2*)(y1 + oi);
        uint2 u2 = *(const uint2*)(y2 + oi);
        float ox = a0 * e.x + iv * (a1 * bf_lo(u1.x) + a2 * bf_lo(u2.x)) + a3 * d * ax;
        float oy = a0 * e.y + iv * (a1 * bf_hi(u1.x) + a2 * bf_hi(u2.x)) + a3 * d * ay;
        float oz = a0 * e.z + iv * (a1 * bf_lo(u1.y) + a2 * bf_lo(u2.y)) + a3 * d * az;
        float ow = a0 * e.w + iv * (a1 * bf_hi(u1.y) + a2 * bf_hi(u2.y)) + a3 * d * aw;
        *(uint2*)(out16 + oi) = make_uint2(f2_to_bf2(ox, oy), f2_to_bf2(oz, ow));
    }
}

// ---------- CSR-ordered dot: 8 lanes per node (8 nodes/wave), stride-1 unroll-4 ----------
__global__ __launch_bounds__(256) void k_dotc(const int* __restrict__ off, const int* __restrict__ rowp,
                                              const int* __restrict__ eidx,
                                              const unsigned short* __restrict__ out16,
                                              float* __restrict__ res, int N, int E) {
    int t = blockIdx.x * blockDim.x + threadIdx.x;
    int wid = t >> 3;
    if (wid >= N) return;
    int q = threadIdx.x & 7;         // dims 8q..8q+7 (uint4 per lane)
    int j0 = off[wid];
    int j1 = (wid == N - 1) ? E : off[wid + 1];

    // col-side operand: 8 lanes x 16B = full 128B row, loaded once
    uint4 bv = *(const uint4*)(out16 + ((size_t)wid << 6) + (q << 3));

    int j = j0;
    for (; j + 3 < j1; j += 4) {
        int r0 = rowp[j],     e0 = eidx[j];
        int r1 = rowp[j + 1], e1 = eidx[j + 1];
        int r2 = rowp[j + 2], e2 = eidx[j + 2];
        int r3 = rowp[j + 3], e3 = eidx[j + 3];
        uint4 a0 = *(const uint4*)(out16 + ((size_t)r0 << 6) + (q << 3));
        uint4 a1 = *(const uint4*)(out16 + ((size_t)r1 << 6) + (q << 3));
        uint4 a2 = *(const uint4*)(out16 + ((size_t)r2 << 6) + (q << 3));
        uint4 a3 = *(const uint4*)(out16 + ((size_t)r3 << 6) + (q << 3));
        float t0 = bf_lo(a0.x) * bf_lo(bv.x) + bf_hi(a0.x) * bf_hi(bv.x)
                 + bf_lo(a0.y) * bf_lo(bv.y) + bf_hi(a0.y) * bf_hi(bv.y)
                 + bf_lo(a0.z) * bf_lo(bv.z) + bf_hi(a0.z) * bf_hi(bv.z)
                 + bf_lo(a0.w) * bf_lo(bv.w) + bf_hi(a0.w) * bf_hi(bv.w);
        float t1 = bf_lo(a1.x) * bf_lo(bv.x) + bf_hi(a1.x) * bf_hi(bv.x)
                 + bf_lo(a1.y) * bf_lo(bv.y) + bf_hi(a1.y) * bf_hi(bv.y)
                 + bf_lo(a1.z) * bf_lo(bv.z) + bf_hi(a1.z) * bf_hi(bv.z)
                 + bf_lo(a1.w) * bf_lo(bv.w) + bf_hi(a1.w) * bf_hi(bv.w);
        float t2 = bf_lo(a2.x) * bf_lo(bv.x) + bf_hi(a2.x) * bf_hi(bv.x)
                 + bf_lo(a2.y) * bf_lo(bv.y) + bf_hi(a2.y) * bf_hi(bv.y)
                 + bf_lo(a2.z) * bf_lo(bv.z) + bf_hi(a2.z) * bf_hi(bv.z)
                 + bf_lo(a2.w) * bf_lo(bv.w) + bf_hi(a2.w) * bf_hi(bv.w);
        float t3 = bf_lo(a3.x) * bf_lo(bv.x) + bf_hi(a3.x) * bf_hi(bv.x)
                 + bf_lo(a3.y) * bf_lo(bv.y) + bf_hi(a3.y) * bf_hi(bv.y)
                 + bf_lo(a3.z) * bf_lo(bv.z) + bf_hi(a3.z) * bf_hi(bv.z)
                 + bf_lo(a3.w) * bf_lo(bv.w) + bf_hi(a3.w) * bf_hi(bv.w);
        t0 += __shfl_xor(t0, 1, 8); t1 += __shfl_xor(t1, 1, 8);
        t2 += __shfl_xor(t2, 1, 8); t3 += __shfl_xor(t3, 1, 8);
        t0 += __shfl_xor(t0, 2, 8); t1 += __shfl_xor(t1, 2, 8);
        t2 += __shfl_xor(t2, 2, 8); t3 += __shfl_xor(t3, 2, 8);
        t0 += __shfl_xor(t0, 4, 8); t1 += __shfl_xor(t1, 4, 8);
        t2 += __shfl_xor(t2, 4, 8); t3 += __shfl_xor(t3, 4, 8);
        if (q == 0) { res[e0] = t0; res[e1] = t1; res[e2] = t2; res[e3] = t3; }
    }
    for (; j < j1; ++j) {
        int r = rowp[j], e = eidx[j];
        uint4 av = *(const uint4*)(out16 + ((size_t)r << 6) + (q << 3));
        float s = bf_lo(av.x) * bf_lo(bv.x) + bf_hi(av.x) * bf_hi(bv.x)
                + bf_lo(av.y) * bf_lo(bv.y) + bf_hi(av.y) * bf_hi(bv.y)
                + bf_lo(av.z) * bf_lo(bv.z) + bf_hi(av.z) * bf_hi(bv.z)
                + bf_lo(av.w) * bf_lo(bv.w) + bf_hi(av.w) * bf_hi(bv.w);
        s += __shfl_xor(s, 1, 8);
        s += __shfl_xor(s, 2, 8);
        s += __shfl_xor(s, 4, 8);
        if (q == 0) res[e] = s;
    }
}

extern "C" void kernel_launch(void* const* d_in, const int* in_sizes, int n_in,
                              void* d_out, int out_size, void* d_ws, size_t ws_size,
                              hipStream_t stream) {
    const int*   edge  = (const int*)d_in[0];     // [2][E]
    const float* emb   = (const float*)d_in[1];   // [N][64]
    const float* alpha = (const float*)d_in[2];   // [4]
    float*       res   = (float*)d_out;           // [E]

    const int E = in_sizes[0] / 2;
    const int N = in_sizes[1] / EDIM;
    const int* row = edge;
    const int* col = edge + E;
    const int NB = (N + BCOLS - 1) >> BSH;        // 196 for N=100k

    // workspace layout (4B words)
    size_t o = 0;
    int*   offA  = (int*)d_ws + o;   o += (size_t)N;
    float* dis   = (float*)d_ws + o; o += (size_t)N;
    float* invd  = (float*)d_ws + o; o += (size_t)N;
    int*   bcur  = (int*)d_ws + o;   o += 256;
    int*   bbase = (int*)d_ws + o;   o += 256;
    int*   rowp  = (int*)d_ws + o;   o += (size_t)E;
    int*   eidx  = (int*)d_ws + o;   o += (size_t)E;
    unsigned short* y0 = (unsigned short*)((int*)d_ws + o); o += (size_t)N * 32;
    unsigned short* y1 = (unsigned short*)((int*)d_ws + o); o += (size_t)N * 32;
    unsigned short* y2 = (unsigned short*)((int*)d_ws + o); o += (size_t)N * 32;
    uint2* pairs = (uint2*)((int*)d_ws + o);      // NB*CAP uint2
    unsigned short* out16 = (unsigned short*)pairs;  // pairs dead after k_binB
    (void)ws_size; (void)n_in;

    const int B = 256;
    const int n16 = N * 16;                       // float4 count of emb

    // CSR build: bin -> scan -> place (emits dis/invd, rowp, eidx)
    k_binit<<<1, 256, 0, stream>>>(bcur, NB);
    k_binA <<<(E + CHUNK - 1) / CHUNK, B, 0, stream>>>(row, col, bcur, pairs, E, NB);
    k_bscan<<<1, 256, 0, stream>>>(bcur, bbase, NB);
    k_binB <<<NB, B, 0, stream>>>(pairs, bcur, bbase, offA, dis, invd, rowp, eidx, N);

    // y0 = bf16(dis * emb)
    k_cvty <<<(n16 + B - 1) / B, B, 0, stream>>>(emb, dis, (unsigned*)y0, n16);

    // three gather layers; last fuses the alpha-combine and emits out16
    k_prop<<<((size_t)N * 16 + B - 1) / B, B, 0, stream>>>(
        offA, rowp, dis, invd, y0, y1, emb, y1, y2, alpha, out16, N, E, 0);
    k_prop<<<((size_t)N * 16 + B - 1) / B, B, 0, stream>>>(
        offA, rowp, dis, invd, y1, y2, emb, y1, y2, alpha, out16, N, E, 0);
    k_prop<<<((size_t)N * 16 + B - 1) / B, B, 0, stream>>>(
        offA, rowp, dis, invd, y2, (unsigned short*)0, emb, y1, y2, alpha, out16, N, E, 1);

    // per-edge dots in CSR order (col operand register-cached)
    k_dotc<<<((size_t)N * 8 + B - 1) / B, B, 0, stream>>>(offA, rowp, eidx, out16, res, N, E);
}

// Round 8
// 181.276 us; speedup vs baseline: 1.7178x; 1.0722x over previous
//
#include <hip/hip_runtime.h>

#define EDIM 64
#define CHUNK 4096          // edges per Phase-A block
#define BSH 9               // bucket = col >> 9  (512 cols/bucket)
#define BCOLS 512
#define CAP 8192            // per-bucket pair capacity (avg ~6400, +22 sigma)
#define PAD 8               // pad node segments to multiple of 8
#define MAXPADB ((PAD - 1) * BCOLS)   // 3584 max padding per bucket

// ---------- bf16 helpers (bit ops, RNE) ----------
__device__ __forceinline__ unsigned f2_to_bf2(float a, float b) {
    unsigned ua = __float_as_uint(a); ua += 0x7fffu + ((ua >> 16) & 1u);
    unsigned ub = __float_as_uint(b); ub += 0x7fffu + ((ub >> 16) & 1u);
    return (ua >> 16) | (ub & 0xffff0000u);
}
__device__ __forceinline__ float bf_lo(unsigned u) { return __uint_as_float(u << 16); }
__device__ __forceinline__ float bf_hi(unsigned u) { return __uint_as_float(u & 0xffff0000u); }

// ---------- bucket cursor init ----------
__global__ void k_binit(int* __restrict__ bcur, int nb) {
    int b = threadIdx.x;
    if (b < nb) bcur[b] = b * CAP;
}

// ---------- Phase A: LDS bucket-sort chunks, coalesced runs ----------
__global__ __launch_bounds__(256) void k_binA(const int* __restrict__ row, const int* __restrict__ col,
                                              int* __restrict__ bcur, uint2* __restrict__ pairs,
                                              int E, int nb) {
    __shared__ uint2 buf[CHUNK];
    __shared__ int histL[256], baseL[256], curL[256], gbaseL[256];
    __shared__ int wsum[4];
    int tid = threadIdx.x;
    int c0 = blockIdx.x * CHUNK;
    int cend = min(CHUNK, E - c0);

    histL[tid] = 0;
    __syncthreads();

    int myr[CHUNK / 256], myc[CHUNK / 256];
    #pragma unroll
    for (int k = 0; k < CHUNK / 256; ++k) {
        int i = k * 256 + tid;
        if (i < cend) {
            int e = c0 + i;
            myr[k] = row[e]; myc[k] = col[e];
            atomicAdd(&histL[myc[k] >> BSH], 1);
        }
    }
    __syncthreads();

    int v = histL[tid];
    int lane = tid & 63, w = tid >> 6;
    int inc = v;
    #pragma unroll
    for (int d = 1; d < 64; d <<= 1) { int t = __shfl_up(inc, d, 64); if (lane >= d) inc += t; }
    if (lane == 63) wsum[w] = inc;
    __syncthreads();
    int woff = 0;
    for (int i = 0; i < w; ++i) woff += wsum[i];
    int excl = inc - v + woff;
    baseL[tid] = excl;
    curL[tid] = excl;
    if (tid < nb) gbaseL[tid] = atomicAdd(&bcur[tid], v);
    __syncthreads();

    #pragma unroll
    for (int k = 0; k < CHUNK / 256; ++k) {
        int i = k * 256 + tid;
        if (i < cend) {
            int b = myc[k] >> BSH;
            int e = c0 + i;
            int pos = atomicAdd(&curL[b], 1);
            buf[pos] = make_uint2((unsigned)myr[k] | ((unsigned)b << 24),
                                  ((unsigned)e << 9) | ((unsigned)myc[k] & (BCOLS - 1)));
        }
    }
    __syncthreads();

    for (int i = tid; i < cend; i += 256) {
        uint2 p = buf[i];
        int b = (int)(p.x >> 24);
        int dst = gbaseL[b] + (i - baseL[b]);
        pairs[dst] = make_uint2(p.x & 0x00FFFFFFu, p.y);
    }
}

// ---------- tiny scan over bucket counts (real counts) ----------
__global__ void k_bscan(const int* __restrict__ bcur, int* __restrict__ bbase, int nb) {
    __shared__ int wsum[4];
    int tid = threadIdx.x;
    int v = (tid < nb) ? (bcur[tid] - tid * CAP) : 0;
    int lane = tid & 63, w = tid >> 6;
    int inc = v;
    #pragma unroll
    for (int d = 1; d < 64; d <<= 1) { int t = __shfl_up(inc, d, 64); if (lane >= d) inc += t; }
    if (lane == 63) wsum[w] = inc;
    __syncthreads();
    int woff = 0;
    for (int i = 0; i < w; ++i) woff += wsum[i];
    if (tid < nb) bbase[tid] = inc - v + woff;
}

// ---------- Phase B: padded per-bucket offsets + dummy fill + placement ----------
__global__ __launch_bounds__(256) void k_binB(const uint2* __restrict__ pairs,
                                              const int* __restrict__ bcur, const int* __restrict__ bbase,
                                              int* __restrict__ offS, int* __restrict__ offE,
                                              float* __restrict__ dis, float* __restrict__ invd,
                                              int* __restrict__ rowp, int* __restrict__ eidx,
                                              int N, int E) {
    __shared__ int degL[BCOLS];
    __shared__ int curL[BCOLS];
    __shared__ int wsum[4];
    int tid = threadIdx.x;
    int b = blockIdx.x;
    int base_in = b * CAP;
    int cnt = bcur[b] - base_in;
    int col0 = b << BSH;
    int ncols = min(BCOLS, N - col0);
    int Pb = bbase[b] + b * MAXPADB;     // padded region base for this bucket

    degL[tid] = 0; degL[tid + 256] = 0;
    __syncthreads();

    for (int i = tid; i < cnt; i += 256)
        atomicAdd(&degL[(int)(pairs[base_in + i].y & (BCOLS - 1))], 1);
    __syncthreads();

    int d0 = degL[2 * tid], d1 = degL[2 * tid + 1];
    int p0 = (d0 + PAD - 1) & ~(PAD - 1);
    int p1 = (d1 + PAD - 1) & ~(PAD - 1);
    int v = p0 + p1;
    int lane = tid & 63, w = tid >> 6;
    int inc = v;
    #pragma unroll
    for (int d = 1; d < 64; d <<= 1) { int t = __shfl_up(inc, d, 64); if (lane >= d) inc += t; }
    if (lane == 63) wsum[w] = inc;
    __syncthreads();
    int woff = 0;
    for (int i = 0; i < w; ++i) woff += wsum[i];
    int exclp = inc - v + woff + Pb;     // padded exclusive offset of col 2*tid
    __syncthreads();
    int c0i = 2 * tid, c1i = 2 * tid + 1;
    if (c0i < ncols) {
        offS[col0 + c0i] = exclp;
        offE[col0 + c0i] = exclp + p0;
        dis [col0 + c0i] = (d0 > 0) ? rsqrtf((float)d0) : 0.0f;
        invd[col0 + c0i] = (d0 > 0) ? sqrtf((float)d0) : 0.0f;
        curL[c0i] = exclp;
        for (int k = d0; k < p0; ++k) { rowp[exclp + k] = N; eidx[exclp + k] = E; }
    }
    if (c1i < ncols) {
        int e1 = exclp + p0;
        offS[col0 + c1i] = e1;
        offE[col0 + c1i] = e1 + p1;
        dis [col0 + c1i] = (d1 > 0) ? rsqrtf((float)d1) : 0.0f;
        invd[col0 + c1i] = (d1 > 0) ? sqrtf((float)d1) : 0.0f;
        curL[c1i] = e1;
        for (int k = d1; k < p1; ++k) { rowp[e1 + k] = N; eidx[e1 + k] = E; }
    }
    __syncthreads();

    for (int i = tid; i < cnt; i += 256) {
        uint2 p = pairs[base_in + i];
        int pos = atomicAdd(&curL[(int)(p.y & (BCOLS - 1))], 1);
        rowp[pos] = (int)p.x;
        eidx[pos] = (int)(p.y >> 9);
    }
}

// ---------- y0 = bf16(dis[n]*emb[n][:]); zero dummy row N of y0/y1/y2 and out16 ----------
__global__ __launch_bounds__(256) void k_cvty(const float* __restrict__ emb,
                                              const float* __restrict__ dis,
                                              unsigned* __restrict__ y0,
                                              unsigned* __restrict__ y1,
                                              unsigned* __restrict__ y2,
                                              unsigned* __restrict__ o16, int N) {
    int i = blockIdx.x * blockDim.x + threadIdx.x;   // one float4 / uint2 per thread
    int n16 = N * 16;
    if (i < n16) {
        float d = dis[i >> 4];
        float4 v = ((const float4*)emb)[i];
        uint2 o; o.x = f2_to_bf2(d * v.x, d * v.y); o.y = f2_to_bf2(d * v.z, d * v.w);
        ((uint2*)y0)[i] = o;
    } else if (i < n16 + 16) {
        uint2 z = make_uint2(0u, 0u);
        ((uint2*)y0)[i] = z;
        ((uint2*)y1)[i] = z;
        ((uint2*)y2)[i] = z;
        ((uint2*)o16)[i] = z;
    }
}

// ---------- gather layer: 8 lanes/node, unroll-8, zero tail (padded CSR) ----------
__global__ __launch_bounds__(256) void k_prop(const int* __restrict__ offS, const int* __restrict__ offE,
                                              const int* __restrict__ rowp,
                                              const float* __restrict__ dis, const float* __restrict__ invd,
                                              const unsigned short* __restrict__ yin,
                                              unsigned short* __restrict__ yout,
                                              const float* __restrict__ emb,
                                              const unsigned short* __restrict__ y1,
                                              const unsigned short* __restrict__ y2,
                                              const float* __restrict__ alpha,
                                              unsigned short* __restrict__ out16,
                                              int N, int last) {
    int t = blockIdx.x * blockDim.x + threadIdx.x;
    int wid = t >> 3;
    if (wid >= N) return;
    int q = threadIdx.x & 7;         // dims 8q..8q+7 (uint4 per lane)
    int j0 = offS[wid];
    int j1 = offE[wid];
    float s0 = 0.f, s1 = 0.f, s2 = 0.f, s3 = 0.f, s4 = 0.f, s5 = 0.f, s6 = 0.f, s7 = 0.f;

    for (int j = j0; j < j1; j += 8) {
        int r0 = rowp[j],     r1 = rowp[j + 1], r2 = rowp[j + 2], r3 = rowp[j + 3];
        int r4 = rowp[j + 4], r5 = rowp[j + 5], r6 = rowp[j + 6], r7 = rowp[j + 7];
        uint4 v0 = *(const uint4*)(yin + ((size_t)r0 << 6) + (q << 3));
        uint4 v1 = *(const uint4*)(yin + ((size_t)r1 << 6) + (q << 3));
        uint4 v2 = *(const uint4*)(yin + ((size_t)r2 << 6) + (q << 3));
        uint4 v3 = *(const uint4*)(yin + ((size_t)r3 << 6) + (q << 3));
        uint4 v4 = *(const uint4*)(yin + ((size_t)r4 << 6) + (q << 3));
        uint4 v5 = *(const uint4*)(yin + ((size_t)r5 << 6) + (q << 3));
        uint4 v6 = *(const uint4*)(yin + ((size_t)r6 << 6) + (q << 3));
        uint4 v7 = *(const uint4*)(yin + ((size_t)r7 << 6) + (q << 3));
        s0 += bf_lo(v0.x) + bf_lo(v1.x) + bf_lo(v2.x) + bf_lo(v3.x)
            + bf_lo(v4.x) + bf_lo(v5.x) + bf_lo(v6.x) + bf_lo(v7.x);
        s1 += bf_hi(v0.x) + bf_hi(v1.x) + bf_hi(v2.x) + bf_hi(v3.x)
            + bf_hi(v4.x) + bf_hi(v5.x) + bf_hi(v6.x) + bf_hi(v7.x);
        s2 += bf_lo(v0.y) + bf_lo(v1.y) + bf_lo(v2.y) + bf_lo(v3.y)
            + bf_lo(v4.y) + bf_lo(v5.y) + bf_lo(v6.y) + bf_lo(v7.y);
        s3 += bf_hi(v0.y) + bf_hi(v1.y) + bf_hi(v2.y) + bf_hi(v3.y)
            + bf_hi(v4.y) + bf_hi(v5.y) + bf_hi(v6.y) + bf_hi(v7.y);
        s4 += bf_lo(v0.z) + bf_lo(v1.z) + bf_lo(v2.z) + bf_lo(v3.z)
            + bf_lo(v4.z) + bf_lo(v5.z) + bf_lo(v6.z) + bf_lo(v7.z);
        s5 += bf_hi(v0.z) + bf_hi(v1.z) + bf_hi(v2.z) + bf_hi(v3.z)
            + bf_hi(v4.z) + bf_hi(v5.z) + bf_hi(v6.z) + bf_hi(v7.z);
        s6 += bf_lo(v0.w) + bf_lo(v1.w) + bf_lo(v2.w) + bf_lo(v3.w)
            + bf_lo(v4.w) + bf_lo(v5.w) + bf_lo(v6.w) + bf_lo(v7.w);
        s7 += bf_hi(v0.w) + bf_hi(v1.w) + bf_hi(v2.w) + bf_hi(v3.w)
            + bf_hi(v4.w) + bf_hi(v5.w) + bf_hi(v6.w) + bf_hi(v7.w);
    }

    float d = dis[wid];
    size_t oi = ((size_t)wid << 6) + (q << 3);
    if (!last) {
        float sc = d * d;
        uint4 o;
        o.x = f2_to_bf2(sc * s0, sc * s1);
        o.y = f2_to_bf2(sc * s2, sc * s3);
        o.z = f2_to_bf2(sc * s4, sc * s5);
        o.w = f2_to_bf2(sc * s6, sc * s7);
        *(uint4*)(yout + oi) = o;
    } else {
        float iv = invd[wid];
        float a0 = alpha[0], a1 = alpha[1], a2 = alpha[2], a3 = alpha[3];
        float4 ea = *(const float4*)(emb + oi);
        float4 eb = *(const float4*)(emb + oi + 4);
        uint4 u1 = *(const uint4*)(y1 + oi);
        uint4 u2 = *(const uint4*)(y2 + oi);
        float o0 = a0 * ea.x + iv * (a1 * bf_lo(u1.x) + a2 * bf_lo(u2.x)) + a3 * d * s0;
        float o1 = a0 * ea.y + iv * (a1 * bf_hi(u1.x) + a2 * bf_hi(u2.x)) + a3 * d * s1;
        float o2 = a0 * ea.z + iv * (a1 * bf_lo(u1.y) + a2 * bf_lo(u2.y)) + a3 * d * s2;
        float o3 = a0 * ea.w + iv * (a1 * bf_hi(u1.y) + a2 * bf_hi(u2.y)) + a3 * d * s3;
        float o4 = a0 * eb.x + iv * (a1 * bf_lo(u1.z) + a2 * bf_lo(u2.z)) + a3 * d * s4;
        float o5 = a0 * eb.y + iv * (a1 * bf_hi(u1.z) + a2 * bf_hi(u2.z)) + a3 * d * s5;
        float o6 = a0 * eb.z + iv * (a1 * bf_lo(u1.w) + a2 * bf_lo(u2.w)) + a3 * d * s6;
        float o7 = a0 * eb.w + iv * (a1 * bf_hi(u1.w) + a2 * bf_hi(u2.w)) + a3 * d * s7;
        uint4 o;
        o.x = f2_to_bf2(o0, o1);
        o.y = f2_to_bf2(o2, o3);
        o.z = f2_to_bf2(o4, o5);
        o.w = f2_to_bf2(o6, o7);
        *(uint4*)(out16 + oi) = o;
    }
}

// ---------- CSR-ordered dot: 8 lanes/node, unroll-8, zero tail; predicated dummy store ----------
__global__ __launch_bounds__(256) void k_dotc(const int* __restrict__ offS, const int* __restrict__ offE,
                                              const int* __restrict__ rowp,
                                              const int* __restrict__ eidx,
                                              const unsigned short* __restrict__ out16,
                                              float* __restrict__ res, int N, int E) {
    int t = blockIdx.x * blockDim.x + threadIdx.x;
    int wid = t >> 3;
    if (wid >= N) return;
    int q = threadIdx.x & 7;         // dims 8q..8q+7 (uint4 per lane)
    int j0 = offS[wid];
    int j1 = offE[wid];

    uint4 bv = *(const uint4*)(out16 + ((size_t)wid << 6) + (q << 3));

    for (int j = j0; j < j1; j += 8) {
        int r0 = rowp[j],     r1 = rowp[j + 1], r2 = rowp[j + 2], r3 = rowp[j + 3];
        int r4 = rowp[j + 4], r5 = rowp[j + 5], r6 = rowp[j + 6], r7 = rowp[j + 7];
        uint4 a0 = *(const uint4*)(out16 + ((size_t)r0 << 6) + (q << 3));
        uint4 a1 = *(const uint4*)(out16 + ((size_t)r1 << 6) + (q << 3));
        uint4 a2 = *(const uint4*)(out16 + ((size_t)r2 << 6) + (q << 3));
        uint4 a3 = *(const uint4*)(out16 + ((size_t)r3 << 6) + (q << 3));
        uint4 a4 = *(const uint4*)(out16 + ((size_t)r4 << 6) + (q << 3));
        uint4 a5 = *(const uint4*)(out16 + ((size_t)r5 << 6) + (q << 3));
        uint4 a6 = *(const uint4*)(out16 + ((size_t)r6 << 6) + (q << 3));
        uint4 a7 = *(const uint4*)(out16 + ((size_t)r7 << 6) + (q << 3));
        #define DOT8(av) (bf_lo(av.x)*bf_lo(bv.x) + bf_hi(av.x)*bf_hi(bv.x) \
                        + bf_lo(av.y)*bf_lo(bv.y) + bf_hi(av.y)*bf_hi(bv.y) \
                        + bf_lo(av.z)*bf_lo(bv.z) + bf_hi(av.z)*bf_hi(bv.z) \
                        + bf_lo(av.w)*bf_lo(bv.w) + bf_hi(av.w)*bf_hi(bv.w))
        float t0 = DOT8(a0), t1 = DOT8(a1), t2 = DOT8(a2), t3 = DOT8(a3);
        float t4 = DOT8(a4), t5 = DOT8(a5), t6 = DOT8(a6), t7 = DOT8(a7);
        #undef DOT8
        t0 += __shfl_xor(t0, 1, 8); t1 += __shfl_xor(t1, 1, 8);
        t2 += __shfl_xor(t2, 1, 8); t3 += __shfl_xor(t3, 1, 8);
        t4 += __shfl_xor(t4, 1, 8); t5 += __shfl_xor(t5, 1, 8);
        t6 += __shfl_xor(t6, 1, 8); t7 += __shfl_xor(t7, 1, 8);
        t0 += __shfl_xor(t0, 2, 8); t1 += __shfl_xor(t1, 2, 8);
        t2 += __shfl_xor(t2, 2, 8); t3 += __shfl_xor(t3, 2, 8);
        t4 += __shfl_xor(t4, 2, 8); t5 += __shfl_xor(t5, 2, 8);
        t6 += __shfl_xor(t6, 2, 8); t7 += __shfl_xor(t7, 2, 8);
        t0 += __shfl_xor(t0, 4, 8); t1 += __shfl_xor(t1, 4, 8);
        t2 += __shfl_xor(t2, 4, 8); t3 += __shfl_xor(t3, 4, 8);
        t4 += __shfl_xor(t4, 4, 8); t5 += __shfl_xor(t5, 4, 8);
        t6 += __shfl_xor(t6, 4, 8); t7 += __shfl_xor(t7, 4, 8);
        if (q == 0) {
            int e0 = eidx[j],     e1 = eidx[j + 1], e2 = eidx[j + 2], e3 = eidx[j + 3];
            int e4 = eidx[j + 4], e5 = eidx[j + 5], e6 = eidx[j + 6], e7 = eidx[j + 7];
            if (e0 < E) res[e0] = t0;
            if (e1 < E) res[e1] = t1;
            if (e2 < E) res[e2] = t2;
            if (e3 < E) res[e3] = t3;
            if (e4 < E) res[e4] = t4;
            if (e5 < E) res[e5] = t5;
            if (e6 < E) res[e6] = t6;
            if (e7 < E) res[e7] = t7;
        }
    }
}

extern "C" void kernel_launch(void* const* d_in, const int* in_sizes, int n_in,
                              void* d_out, int out_size, void* d_ws, size_t ws_size,
                              hipStream_t stream) {
    const int*   edge  = (const int*)d_in[0];     // [2][E]
    const float* emb   = (const float*)d_in[1];   // [N][64]
    const float* alpha = (const float*)d_in[2];   // [4]
    float*       res   = (float*)d_out;           // [E]

    const int E = in_sizes[0] / 2;
    const int N = in_sizes[1] / EDIM;
    const int* row = edge;
    const int* col = edge + E;
    const int NB = (N + BCOLS - 1) >> BSH;        // 196 for N=100k
    const size_t EPAD = (size_t)E + (size_t)NB * MAXPADB + 64;  // padded CSR capacity

    // workspace layout (4B words)
    size_t o = 0;
    int*   offS  = (int*)d_ws + o;   o += (size_t)N;
    int*   offE  = (int*)d_ws + o;   o += (size_t)N;
    float* dis   = (float*)d_ws + o; o += (size_t)N;
    float* invd  = (float*)d_ws + o; o += (size_t)N;
    int*   bcur  = (int*)d_ws + o;   o += 256;
    int*   bbase = (int*)d_ws + o;   o += 256;
    int*   rowp  = (int*)d_ws + o;   o += EPAD;
    int*   eidx  = (int*)d_ws + o;   o += EPAD;
    unsigned short* y0 = (unsigned short*)((int*)d_ws + o); o += (size_t)(N + 1) * 32;
    unsigned short* y1 = (unsigned short*)((int*)d_ws + o); o += (size_t)(N + 1) * 32;
    unsigned short* y2 = (unsigned short*)((int*)d_ws + o); o += (size_t)(N + 1) * 32;
    uint2* pairs = (uint2*)((int*)d_ws + o);      // NB*CAP uint2 (12.85 MB)
    unsigned short* out16 = (unsigned short*)pairs;  // pairs dead after k_binB; holds N+1 rows
    (void)ws_size; (void)n_in;

    const int B = 256;

    // CSR build: bin -> scan -> padded place (emits dis/invd, offS/offE, rowp, eidx)
    k_binit<<<1, 256, 0, stream>>>(bcur, NB);
    k_binA <<<(E + CHUNK - 1) / CHUNK, B, 0, stream>>>(row, col, bcur, pairs, E, NB);
    k_bscan<<<1, 256, 0, stream>>>(bcur, bbase, NB);
    k_binB <<<NB, B, 0, stream>>>(pairs, bcur, bbase, offS, offE, dis, invd, rowp, eidx, N, E);

    // y0 = bf16(dis * emb); zero dummy rows
    k_cvty <<<(N * 16 + 16 + B - 1) / B, B, 0, stream>>>(emb, dis, (unsigned*)y0,
                                                         (unsigned*)y1, (unsigned*)y2,
                                                         (unsigned*)out16, N);

    // three gather layers; last fuses the alpha-combine and emits out16
    k_prop<<<((size_t)N * 8 + B - 1) / B, B, 0, stream>>>(
        offS, offE, rowp, dis, invd, y0, y1, emb, y1, y2, alpha, out16, N, 0);
    k_prop<<<((size_t)N * 8 + B - 1) / B, B, 0, stream>>>(
        offS, offE, rowp, dis, invd, y1, y2, emb, y1, y2, alpha, out16, N, 0);
    k_prop<<<((size_t)N * 8 + B - 1) / B, B, 0, stream>>>(
        offS, offE, rowp, dis, invd, y2, (unsigned short*)0, emb, y1, y2, alpha, out16, N, 1);

    // per-edge dots in CSR order (padded, predicated stores)
    k_dotc<<<((size_t)N * 8 + B - 1) / B, B, 0, stream>>>(offS, offE, rowp, eidx, out16, res, N, E);
}

// Round 9
// 180.827 us; speedup vs baseline: 1.7221x; 1.0025x over previous
//
#include <hip/hip_runtime.h>

#define EDIM 64
#define CHUNK 4096          // edges per Phase-A block
#define BSH 9               // bucket = col >> 9  (512 cols/bucket)
#define BCOLS 512
#define CAP 8192            // per-bucket pair capacity (avg ~6400, +22 sigma)
#define PAD 8               // pad node segments to multiple of 8
#define MAXPADB ((PAD - 1) * BCOLS)   // 3584 max padding per bucket

// ---------- bf16 helpers (bit ops, RNE) ----------
__device__ __forceinline__ unsigned f2_to_bf2(float a, float b) {
    unsigned ua = __float_as_uint(a); ua += 0x7fffu + ((ua >> 16) & 1u);
    unsigned ub = __float_as_uint(b); ub += 0x7fffu + ((ub >> 16) & 1u);
    return (ua >> 16) | (ub & 0xffff0000u);
}
__device__ __forceinline__ float bf_lo(unsigned u) { return __uint_as_float(u << 16); }
__device__ __forceinline__ float bf_hi(unsigned u) { return __uint_as_float(u & 0xffff0000u); }

// ---------- bucket cursor init ----------
__global__ void k_binit(int* __restrict__ bcur, int nb) {
    int b = threadIdx.x;
    if (b < nb) bcur[b] = b * CAP;
}

// ---------- Phase A: LDS bucket-sort chunks, coalesced runs ----------
__global__ __launch_bounds__(256) void k_binA(const int* __restrict__ row, const int* __restrict__ col,
                                              int* __restrict__ bcur, uint2* __restrict__ pairs,
                                              int E, int nb) {
    __shared__ uint2 buf[CHUNK];
    __shared__ int histL[256], baseL[256], curL[256], gbaseL[256];
    __shared__ int wsum[4];
    int tid = threadIdx.x;
    int c0 = blockIdx.x * CHUNK;
    int cend = min(CHUNK, E - c0);

    histL[tid] = 0;
    __syncthreads();

    int myr[CHUNK / 256], myc[CHUNK / 256];
    #pragma unroll
    for (int k = 0; k < CHUNK / 256; ++k) {
        int i = k * 256 + tid;
        if (i < cend) {
            int e = c0 + i;
            myr[k] = row[e]; myc[k] = col[e];
            atomicAdd(&histL[myc[k] >> BSH], 1);
        }
    }
    __syncthreads();

    int v = histL[tid];
    int lane = tid & 63, w = tid >> 6;
    int inc = v;
    #pragma unroll
    for (int d = 1; d < 64; d <<= 1) { int t = __shfl_up(inc, d, 64); if (lane >= d) inc += t; }
    if (lane == 63) wsum[w] = inc;
    __syncthreads();
    int woff = 0;
    for (int i = 0; i < w; ++i) woff += wsum[i];
    int excl = inc - v + woff;
    baseL[tid] = excl;
    curL[tid] = excl;
    if (tid < nb) gbaseL[tid] = atomicAdd(&bcur[tid], v);
    __syncthreads();

    #pragma unroll
    for (int k = 0; k < CHUNK / 256; ++k) {
        int i = k * 256 + tid;
        if (i < cend) {
            int b = myc[k] >> BSH;
            int e = c0 + i;
            int pos = atomicAdd(&curL[b], 1);
            buf[pos] = make_uint2((unsigned)myr[k] | ((unsigned)b << 24),
                                  ((unsigned)e << 9) | ((unsigned)myc[k] & (BCOLS - 1)));
        }
    }
    __syncthreads();

    for (int i = tid; i < cend; i += 256) {
        uint2 p = buf[i];
        int b = (int)(p.x >> 24);
        int dst = gbaseL[b] + (i - baseL[b]);
        pairs[dst] = make_uint2(p.x & 0x00FFFFFFu, p.y);
    }
}

// ---------- Phase B: inline bucket-scan + padded offsets + placement + y0 emission ----------
__global__ __launch_bounds__(256) void k_binB(const uint2* __restrict__ pairs,
                                              const int* __restrict__ bcur,
                                              int* __restrict__ offS, int* __restrict__ offE,
                                              float* __restrict__ dis, float* __restrict__ invd,
                                              int* __restrict__ rowp, int* __restrict__ eidx,
                                              const float* __restrict__ emb,
                                              unsigned* __restrict__ y0, unsigned* __restrict__ y1,
                                              unsigned* __restrict__ y2, unsigned* __restrict__ o16,
                                              int N, int E, int NB) {
    __shared__ int degL[BCOLS];
    __shared__ int curL[BCOLS];
    __shared__ float disL[BCOLS];
    __shared__ int wsum[4];
    __shared__ int bbaseS;
    int tid = threadIdx.x;
    int b = blockIdx.x;
    int base_in = b * CAP;
    int cnt = bcur[b] - base_in;
    int col0 = b << BSH;
    int ncols = min(BCOLS, N - col0);

    degL[tid] = 0; degL[tid + 256] = 0;

    // inline exclusive scan of real bucket counts -> this block's base
    {
        int v = (tid < NB) ? (bcur[tid] - tid * CAP) : 0;
        int lane = tid & 63, w = tid >> 6;
        int inc = v;
        #pragma unroll
        for (int d = 1; d < 64; d <<= 1) { int t = __shfl_up(inc, d, 64); if (lane >= d) inc += t; }
        if (lane == 63) wsum[w] = inc;
        __syncthreads();                 // wsum ready; degL zeroed
        int woff = 0;
        for (int i = 0; i < w; ++i) woff += wsum[i];
        if (tid == b) bbaseS = inc - v + woff;
    }
    __syncthreads();                     // bbaseS visible

    for (int i = tid; i < cnt; i += 256)
        atomicAdd(&degL[(int)(pairs[base_in + i].y & (BCOLS - 1))], 1);
    __syncthreads();

    int Pb = bbaseS + b * MAXPADB;       // padded region base for this bucket
    int d0 = degL[2 * tid], d1 = degL[2 * tid + 1];
    int p0 = (d0 + PAD - 1) & ~(PAD - 1);
    int p1 = (d1 + PAD - 1) & ~(PAD - 1);
    int v = p0 + p1;
    int lane = tid & 63, w = tid >> 6;
    int inc = v;
    #pragma unroll
    for (int d = 1; d < 64; d <<= 1) { int t = __shfl_up(inc, d, 64); if (lane >= d) inc += t; }
    if (lane == 63) wsum[w] = inc;
    __syncthreads();
    int woff = 0;
    for (int i = 0; i < w; ++i) woff += wsum[i];
    int exclp = inc - v + woff + Pb;     // padded exclusive offset of col 2*tid
    __syncthreads();
    int c0i = 2 * tid, c1i = 2 * tid + 1;
    if (c0i < ncols) {
        float dv = (d0 > 0) ? rsqrtf((float)d0) : 0.0f;
        offS[col0 + c0i] = exclp;
        offE[col0 + c0i] = exclp + p0;
        dis [col0 + c0i] = dv;
        invd[col0 + c0i] = (d0 > 0) ? sqrtf((float)d0) : 0.0f;
        disL[c0i] = dv;
        curL[c0i] = exclp;
        for (int k = d0; k < p0; ++k) { rowp[exclp + k] = N; eidx[exclp + k] = E; }
    }
    if (c1i < ncols) {
        float dv = (d1 > 0) ? rsqrtf((float)d1) : 0.0f;
        int e1 = exclp + p0;
        offS[col0 + c1i] = e1;
        offE[col0 + c1i] = e1 + p1;
        dis [col0 + c1i] = dv;
        invd[col0 + c1i] = (d1 > 0) ? sqrtf((float)d1) : 0.0f;
        disL[c1i] = dv;
        curL[c1i] = e1;
        for (int k = d1; k < p1; ++k) { rowp[e1 + k] = N; eidx[e1 + k] = E; }
    }
    __syncthreads();

    // placement
    for (int i = tid; i < cnt; i += 256) {
        uint2 p = pairs[base_in + i];
        int pos = atomicAdd(&curL[(int)(p.y & (BCOLS - 1))], 1);
        rowp[pos] = (int)p.x;
        eidx[pos] = (int)(p.y >> 9);
    }

    // fused y0 emission: y0[c] = bf16(dis[c] * emb[c][:]) for this bucket's cols
    for (int i = tid; i < ncols * 16; i += 256) {
        int r = i >> 4, u = i & 15;
        float dv = disL[r];
        float4 vv = ((const float4*)(emb + ((size_t)(col0 + r) << 6)))[u];
        uint2 ov;
        ov.x = f2_to_bf2(dv * vv.x, dv * vv.y);
        ov.y = f2_to_bf2(dv * vv.z, dv * vv.w);
        ((uint2*)y0)[((size_t)(col0 + r) << 4) + u] = ov;
    }
    // dummy row N (zero) for all gather targets
    if (b == 0 && tid < 16) {
        uint2 z = make_uint2(0u, 0u);
        size_t di = ((size_t)N << 4) + tid;
        ((uint2*)y0)[di] = z;
        ((uint2*)y1)[di] = z;
        ((uint2*)y2)[di] = z;
        ((uint2*)o16)[di] = z;
    }
}

// ---------- gather layer: 8 lanes/node, unroll-8, rowp software-pipelined ----------
__global__ __launch_bounds__(256) void k_prop(const int* __restrict__ offS, const int* __restrict__ offE,
                                              const int* __restrict__ rowp,
                                              const float* __restrict__ dis, const float* __restrict__ invd,
                                              const unsigned short* __restrict__ yin,
                                              unsigned short* __restrict__ yout,
                                              const float* __restrict__ emb,
                                              const unsigned short* __restrict__ y1,
                                              const unsigned short* __restrict__ y2,
                                              const float* __restrict__ alpha,
                                              unsigned short* __restrict__ out16,
                                              int N, int last) {
    int t = blockIdx.x * blockDim.x + threadIdx.x;
    int wid = t >> 3;
    if (wid >= N) return;
    int q = threadIdx.x & 7;         // dims 8q..8q+7 (uint4 per lane)
    int j0 = offS[wid];
    int j1 = offE[wid];
    float s0 = 0.f, s1 = 0.f, s2 = 0.f, s3 = 0.f, s4 = 0.f, s5 = 0.f, s6 = 0.f, s7 = 0.f;

    // preload first batch of row indices (safe: rowp has slack beyond last segment)
    int rc0 = rowp[j0],     rc1 = rowp[j0 + 1], rc2 = rowp[j0 + 2], rc3 = rowp[j0 + 3];
    int rc4 = rowp[j0 + 4], rc5 = rowp[j0 + 5], rc6 = rowp[j0 + 6], rc7 = rowp[j0 + 7];

    for (int j = j0; j < j1; j += 8) {
        uint4 v0 = *(const uint4*)(yin + ((size_t)rc0 << 6) + (q << 3));
        uint4 v1 = *(const uint4*)(yin + ((size_t)rc1 << 6) + (q << 3));
        uint4 v2 = *(const uint4*)(yin + ((size_t)rc2 << 6) + (q << 3));
        uint4 v3 = *(const uint4*)(yin + ((size_t)rc3 << 6) + (q << 3));
        uint4 v4 = *(const uint4*)(yin + ((size_t)rc4 << 6) + (q << 3));
        uint4 v5 = *(const uint4*)(yin + ((size_t)rc5 << 6) + (q << 3));
        uint4 v6 = *(const uint4*)(yin + ((size_t)rc6 << 6) + (q << 3));
        uint4 v7 = *(const uint4*)(yin + ((size_t)rc7 << 6) + (q << 3));
        // prefetch next batch of indices while data loads are in flight
        int nj = j + 8;
        rc0 = rowp[nj];     rc1 = rowp[nj + 1]; rc2 = rowp[nj + 2]; rc3 = rowp[nj + 3];
        rc4 = rowp[nj + 4]; rc5 = rowp[nj + 5]; rc6 = rowp[nj + 6]; rc7 = rowp[nj + 7];
        s0 += bf_lo(v0.x) + bf_lo(v1.x) + bf_lo(v2.x) + bf_lo(v3.x)
            + bf_lo(v4.x) + bf_lo(v5.x) + bf_lo(v6.x) + bf_lo(v7.x);
        s1 += bf_hi(v0.x) + bf_hi(v1.x) + bf_hi(v2.x) + bf_hi(v3.x)
            + bf_hi(v4.x) + bf_hi(v5.x) + bf_hi(v6.x) + bf_hi(v7.x);
        s2 += bf_lo(v0.y) + bf_lo(v1.y) + bf_lo(v2.y) + bf_lo(v3.y)
            + bf_lo(v4.y) + bf_lo(v5.y) + bf_lo(v6.y) + bf_lo(v7.y);
        s3 += bf_hi(v0.y) + bf_hi(v1.y) + bf_hi(v2.y) + bf_hi(v3.y)
            + bf_hi(v4.y) + bf_hi(v5.y) + bf_hi(v6.y) + bf_hi(v7.y);
        s4 += bf_lo(v0.z) + bf_lo(v1.z) + bf_lo(v2.z) + bf_lo(v3.z)
            + bf_lo(v4.z) + bf_lo(v5.z) + bf_lo(v6.z) + bf_lo(v7.z);
        s5 += bf_hi(v0.z) + bf_hi(v1.z) + bf_hi(v2.z) + bf_hi(v3.z)
            + bf_hi(v4.z) + bf_hi(v5.z) + bf_hi(v6.z) + bf_hi(v7.z);
        s6 += bf_lo(v0.w) + bf_lo(v1.w) + bf_lo(v2.w) + bf_lo(v3.w)
            + bf_lo(v4.w) + bf_lo(v5.w) + bf_lo(v6.w) + bf_lo(v7.w);
        s7 += bf_hi(v0.w) + bf_hi(v1.w) + bf_hi(v2.w) + bf_hi(v3.w)
            + bf_hi(v4.w) + bf_hi(v5.w) + bf_hi(v6.w) + bf_hi(v7.w);
    }

    float d = dis[wid];
    size_t oi = ((size_t)wid << 6) + (q << 3);
    if (!last) {
        float sc = d * d;
        uint4 o;
        o.x = f2_to_bf2(sc * s0, sc * s1);
        o.y = f2_to_bf2(sc * s2, sc * s3);
        o.z = f2_to_bf2(sc * s4, sc * s5);
        o.w = f2_to_bf2(sc * s6, sc * s7);
        *(uint4*)(yout + oi) = o;
    } else {
        float iv = invd[wid];
        float a0 = alpha[0], a1 = alpha[1], a2 = alpha[2], a3 = alpha[3];
        float4 ea = *(const float4*)(emb + oi);
        float4 eb = *(const float4*)(emb + oi + 4);
        uint4 u1 = *(const uint4*)(y1 + oi);
        uint4 u2 = *(const uint4*)(y2 + oi);
        float o0 = a0 * ea.x + iv * (a1 * bf_lo(u1.x) + a2 * bf_lo(u2.x)) + a3 * d * s0;
        float o1 = a0 * ea.y + iv * (a1 * bf_hi(u1.x) + a2 * bf_hi(u2.x)) + a3 * d * s1;
        float o2 = a0 * ea.z + iv * (a1 * bf_lo(u1.y) + a2 * bf_lo(u2.y)) + a3 * d * s2;
        float o3 = a0 * ea.w + iv * (a1 * bf_hi(u1.y) + a2 * bf_hi(u2.y)) + a3 * d * s3;
        float o4 = a0 * eb.x + iv * (a1 * bf_lo(u1.z) + a2 * bf_lo(u2.z)) + a3 * d * s4;
        float o5 = a0 * eb.y + iv * (a1 * bf_hi(u1.z) + a2 * bf_hi(u2.z)) + a3 * d * s5;
        float o6 = a0 * eb.z + iv * (a1 * bf_lo(u1.w) + a2 * bf_lo(u2.w)) + a3 * d * s6;
        float o7 = a0 * eb.w + iv * (a1 * bf_hi(u1.w) + a2 * bf_hi(u2.w)) + a3 * d * s7;
        uint4 o;
        o.x = f2_to_bf2(o0, o1);
        o.y = f2_to_bf2(o2, o3);
        o.z = f2_to_bf2(o4, o5);
        o.w = f2_to_bf2(o6, o7);
        *(uint4*)(out16 + oi) = o;
    }
}

// ---------- CSR-ordered dot: 8 lanes/node, unroll-8, pipelined, nontemporal res ----------
__global__ __launch_bounds__(256) void k_dotc(const int* __restrict__ offS, const int* __restrict__ offE,
                                              const int* __restrict__ rowp,
                                              const int* __restrict__ eidx,
                                              const unsigned short* __restrict__ out16,
                                              float* __restrict__ res, int N, int E) {
    int t = blockIdx.x * blockDim.x + threadIdx.x;
    int wid = t >> 3;
    if (wid >= N) return;
    int q = threadIdx.x & 7;         // dims 8q..8q+7 (uint4 per lane)
    int j0 = offS[wid];
    int j1 = offE[wid];

    uint4 bv = *(const uint4*)(out16 + ((size_t)wid << 6) + (q << 3));

    int rc0 = rowp[j0],     rc1 = rowp[j0 + 1], rc2 = rowp[j0 + 2], rc3 = rowp[j0 + 3];
    int rc4 = rowp[j0 + 4], rc5 = rowp[j0 + 5], rc6 = rowp[j0 + 6], rc7 = rowp[j0 + 7];

    for (int j = j0; j < j1; j += 8) {
        uint4 a0 = *(const uint4*)(out16 + ((size_t)rc0 << 6) + (q << 3));
        uint4 a1 = *(const uint4*)(out16 + ((size_t)rc1 << 6) + (q << 3));
        uint4 a2 = *(const uint4*)(out16 + ((size_t)rc2 << 6) + (q << 3));
        uint4 a3 = *(const uint4*)(out16 + ((size_t)rc3 << 6) + (q << 3));
        uint4 a4 = *(const uint4*)(out16 + ((size_t)rc4 << 6) + (q << 3));
        uint4 a5 = *(const uint4*)(out16 + ((size_t)rc5 << 6) + (q << 3));
        uint4 a6 = *(const uint4*)(out16 + ((size_t)rc6 << 6) + (q << 3));
        uint4 a7 = *(const uint4*)(out16 + ((size_t)rc7 << 6) + (q << 3));
        int nj = j + 8;
        rc0 = rowp[nj];     rc1 = rowp[nj + 1]; rc2 = rowp[nj + 2]; rc3 = rowp[nj + 3];
        rc4 = rowp[nj + 4]; rc5 = rowp[nj + 5]; rc6 = rowp[nj + 6]; rc7 = rowp[nj + 7];
        #define DOT8(av) (bf_lo(av.x)*bf_lo(bv.x) + bf_hi(av.x)*bf_hi(bv.x) \
                        + bf_lo(av.y)*bf_lo(bv.y) + bf_hi(av.y)*bf_hi(bv.y) \
                        + bf_lo(av.z)*bf_lo(bv.z) + bf_hi(av.z)*bf_hi(bv.z) \
                        + bf_lo(av.w)*bf_lo(bv.w) + bf_hi(av.w)*bf_hi(bv.w))
        float t0 = DOT8(a0), t1 = DOT8(a1), t2 = DOT8(a2), t3 = DOT8(a3);
        float t4 = DOT8(a4), t5 = DOT8(a5), t6 = DOT8(a6), t7 = DOT8(a7);
        #undef DOT8
        t0 += __shfl_xor(t0, 1, 8); t1 += __shfl_xor(t1, 1, 8);
        t2 += __shfl_xor(t2, 1, 8); t3 += __shfl_xor(t3, 1, 8);
        t4 += __shfl_xor(t4, 1, 8); t5 += __shfl_xor(t5, 1, 8);
        t6 += __shfl_xor(t6, 1, 8); t7 += __shfl_xor(t7, 1, 8);
        t0 += __shfl_xor(t0, 2, 8); t1 += __shfl_xor(t1, 2, 8);
        t2 += __shfl_xor(t2, 2, 8); t3 += __shfl_xor(t3, 2, 8);
        t4 += __shfl_xor(t4, 2, 8); t5 += __shfl_xor(t5, 2, 8);
        t6 += __shfl_xor(t6, 2, 8); t7 += __shfl_xor(t7, 2, 8);
        t0 += __shfl_xor(t0, 4, 8); t1 += __shfl_xor(t1, 4, 8);
        t2 += __shfl_xor(t2, 4, 8); t3 += __shfl_xor(t3, 4, 8);
        t4 += __shfl_xor(t4, 4, 8); t5 += __shfl_xor(t5, 4, 8);
        t6 += __shfl_xor(t6, 4, 8); t7 += __shfl_xor(t7, 4, 8);
        if (q == 0) {
            int e0 = eidx[j],     e1 = eidx[j + 1], e2 = eidx[j + 2], e3 = eidx[j + 3];
            int e4 = eidx[j + 4], e5 = eidx[j + 5], e6 = eidx[j + 6], e7 = eidx[j + 7];
            if (e0 < E) __builtin_nontemporal_store(t0, &res[e0]);
            if (e1 < E) __builtin_nontemporal_store(t1, &res[e1]);
            if (e2 < E) __builtin_nontemporal_store(t2, &res[e2]);
            if (e3 < E) __builtin_nontemporal_store(t3, &res[e3]);
            if (e4 < E) __builtin_nontemporal_store(t4, &res[e4]);
            if (e5 < E) __builtin_nontemporal_store(t5, &res[e5]);
            if (e6 < E) __builtin_nontemporal_store(t6, &res[e6]);
            if (e7 < E) __builtin_nontemporal_store(t7, &res[e7]);
        }
    }
}

extern "C" void kernel_launch(void* const* d_in, const int* in_sizes, int n_in,
                              void* d_out, int out_size, void* d_ws, size_t ws_size,
                              hipStream_t stream) {
    const int*   edge  = (const int*)d_in[0];     // [2][E]
    const float* emb   = (const float*)d_in[1];   // [N][64]
    const float* alpha = (const float*)d_in[2];   // [4]
    float*       res   = (float*)d_out;           // [E]

    const int E = in_sizes[0] / 2;
    const int N = in_sizes[1] / EDIM;
    const int* row = edge;
    const int* col = edge + E;
    const int NB = (N + BCOLS - 1) >> BSH;        // 196 for N=100k
    const size_t EPAD = (size_t)E + (size_t)NB * MAXPADB + 64;  // padded CSR capacity

    // workspace layout (4B words)
    size_t o = 0;
    int*   offS  = (int*)d_ws + o;   o += (size_t)N;
    int*   offE  = (int*)d_ws + o;   o += (size_t)N;
    float* dis   = (float*)d_ws + o; o += (size_t)N;
    float* invd  = (float*)d_ws + o; o += (size_t)N;
    int*   bcur  = (int*)d_ws + o;   o += 256;
    int*   rowp  = (int*)d_ws + o;   o += EPAD;
    int*   eidx  = (int*)d_ws + o;   o += EPAD;
    unsigned short* y0 = (unsigned short*)((int*)d_ws + o); o += (size_t)(N + 1) * 32;
    unsigned short* y1 = (unsigned short*)((int*)d_ws + o); o += (size_t)(N + 1) * 32;
    unsigned short* y2 = (unsigned short*)((int*)d_ws + o); o += (size_t)(N + 1) * 32;
    uint2* pairs = (uint2*)((int*)d_ws + o);      // NB*CAP uint2 (12.85 MB)
    unsigned short* out16 = (unsigned short*)pairs;  // pairs dead after k_binB; holds N+1 rows
    (void)ws_size; (void)n_in;

    const int B = 256;

    // CSR build: bin -> padded place (+ inline scan, dis/invd, y0 emission, dummy rows)
    k_binit<<<1, 256, 0, stream>>>(bcur, NB);
    k_binA <<<(E + CHUNK - 1) / CHUNK, B, 0, stream>>>(row, col, bcur, pairs, E, NB);
    k_binB <<<NB, B, 0, stream>>>(pairs, bcur, offS, offE, dis, invd, rowp, eidx,
                                  emb, (unsigned*)y0, (unsigned*)y1, (unsigned*)y2,
                                  (unsigned*)out16, N, E, NB);

    // three gather layers; last fuses the alpha-combine and emits out16
    k_prop<<<((size_t)N * 8 + B - 1) / B, B, 0, stream>>>(
        offS, offE, rowp, dis, invd, y0, y1, emb, y1, y2, alpha, out16, N, 0);
    k_prop<<<((size_t)N * 8 + B - 1) / B, B, 0, stream>>>(
        offS, offE, rowp, dis, invd, y1, y2, emb, y1, y2, alpha, out16, N, 0);
    k_prop<<<((size_t)N * 8 + B - 1) / B, B, 0, stream>>>(
        offS, offE, rowp, dis, invd, y2, (unsigned short*)0, emb, y1, y2, alpha, out16, N, 1);

    // per-edge dots in CSR order (padded, predicated nontemporal stores)
    k_dotc<<<((size_t)N * 8 + B - 1) / B, B, 0, stream>>>(offS, offE, rowp, eidx, out16, res, N, E);
}